// Round 10
// baseline (43.305 us; speedup 1.0000x reference)
//
#include <hip/hip_runtime.h>

#define IW 4096
#define IH 4096
#define OH 4094
#define OW 4094
#define CG 512               // col-groups per row (8 cols each)
#define NWG 2048             // (512 * 1024) / 256
#define XCHUNK 256           // NWG / 8

typedef float f32x4 __attribute__((ext_vector_type(4)));
typedef float f32x2 __attribute__((ext_vector_type(2)));

__global__ __launch_bounds__(256) void conv3x3_c8r4(
    const float* __restrict__ in, const float* __restrict__ wgt,
    const float* __restrict__ bias, float* __restrict__ out) {

    // XCD-aware bijective swizzle (2048 % 8 == 0).
    int b   = blockIdx.x;
    int swz = (b & 7) * XCHUNK + (b >> 3);
    int idx = swz * 256 + (int)threadIdx.x;

    int cg   = idx & (CG - 1);
    int rg   = idx >> 9;           // uniform within a block
    int x    = cg << 3;            // output col start (multiple of 8)
    int row0 = rg << 2;            // output row start (even)

    float wv[9];
#pragma unroll
    for (int i = 0; i < 9; ++i) wv[i] = wgt[i];
    float bs = bias[0];

    int nr    = (row0 + 4 <= OH) ? 4 : (OH - row0);  // 4, or 2 at rg==1023 (uniform)
    int nload = nr + 2;

    // 6 input row-segments of 10 floats: 2x aligned f32x4 + f32x2 tail.
    float r[6][10];
#pragma unroll
    for (int t = 0; t < 6; ++t) {
        if (t < nload) {
            const float* rp = in + (size_t)(row0 + t) * IW + x;
            f32x4 a = *reinterpret_cast<const f32x4*>(rp);       // 32B-aligned
            f32x4 c = *reinterpret_cast<const f32x4*>(rp + 4);   // 16B-aligned
#pragma unroll
            for (int j = 0; j < 4; ++j) { r[t][j] = a[j]; r[t][4 + j] = c[j]; }
            if (x + 9 < IW) {                                    // false only at cg==511
                f32x2 e = *reinterpret_cast<const f32x2*>(rp + 8);
                r[t][8] = e[0]; r[t][9] = e[1];
            } else { r[t][8] = 0.f; r[t][9] = 0.f; }
        } else {
#pragma unroll
            for (int j = 0; j < 10; ++j) r[t][j] = 0.f;
        }
    }

    float acc[4][8];
#pragma unroll
    for (int i = 0; i < 4; ++i)
#pragma unroll
        for (int c = 0; c < 8; ++c) acc[i][c] = bs;

#pragma unroll
    for (int orow = 0; orow < 4; ++orow) {
#pragma unroll
        for (int kh = 0; kh < 3; ++kh) {
            int t = orow + kh;
            float w0 = wv[kh * 3 + 0], w1 = wv[kh * 3 + 1], w2 = wv[kh * 3 + 2];
#pragma unroll
            for (int c = 0; c < 8; ++c)
                acc[orow][c] += w0 * r[t][c] + w1 * r[t][c + 1] + w2 * r[t][c + 2];
        }
    }

    // Stores (nontemporal). row0 even => even orow rows 16B-aligned at 4x (x%8==0),
    // odd orow rows are ...%16 == 8 (so f32x2 / f32x4 / f32x2 split is aligned).
    int nc = (x + 8 <= OW) ? 8 : (OW - x);   // 8, or 6 at cg==511 (1 lane/wave)
#pragma unroll
    for (int orow = 0; orow < 4; ++orow) {
        if (orow < nr) {
            float* op = out + (size_t)(row0 + orow) * OW + x;
            if ((orow & 1) == 0) {
                if (nc == 8) {
                    f32x4 v0 = { acc[orow][0], acc[orow][1], acc[orow][2], acc[orow][3] };
                    f32x4 v1 = { acc[orow][4], acc[orow][5], acc[orow][6], acc[orow][7] };
                    __builtin_nontemporal_store(v0, reinterpret_cast<f32x4*>(op));
                    __builtin_nontemporal_store(v1, reinterpret_cast<f32x4*>(op + 4));
                } else {
                    f32x4 v0 = { acc[orow][0], acc[orow][1], acc[orow][2], acc[orow][3] };
                    f32x2 v1 = { acc[orow][4], acc[orow][5] };
                    __builtin_nontemporal_store(v0, reinterpret_cast<f32x4*>(op));
                    __builtin_nontemporal_store(v1, reinterpret_cast<f32x2*>(op + 4));
                }
            } else {
                if (nc == 8) {
                    f32x2 v0 = { acc[orow][0], acc[orow][1] };
                    f32x4 v1 = { acc[orow][2], acc[orow][3], acc[orow][4], acc[orow][5] };
                    f32x2 v2 = { acc[orow][6], acc[orow][7] };
                    __builtin_nontemporal_store(v0, reinterpret_cast<f32x2*>(op));
                    __builtin_nontemporal_store(v1, reinterpret_cast<f32x4*>(op + 2));
                    __builtin_nontemporal_store(v2, reinterpret_cast<f32x2*>(op + 6));
                } else {
                    f32x2 v0 = { acc[orow][0], acc[orow][1] };
                    f32x4 v1 = { acc[orow][2], acc[orow][3], acc[orow][4], acc[orow][5] };
                    __builtin_nontemporal_store(v0, reinterpret_cast<f32x2*>(op));
                    __builtin_nontemporal_store(v1, reinterpret_cast<f32x4*>(op + 2));
                }
            }
        }
    }
}

extern "C" void kernel_launch(void* const* d_in, const int* in_sizes, int n_in,
                              void* d_out, int out_size, void* d_ws, size_t ws_size,
                              hipStream_t stream) {
    const float* in   = (const float*)d_in[0];
    const float* wgt  = (const float*)d_in[1];
    const float* bias = (const float*)d_in[2];
    float* out        = (float*)d_out;

    conv3x3_c8r4<<<NWG, 256, 0, stream>>>(in, wgt, bias, out);
}

// Round 11
// 28.663 us; speedup vs baseline: 1.5109x; 1.5109x over previous
//
#include <hip/hip_runtime.h>

#define IW 4096
#define IH 4096
#define OH 4094
#define OW 4094
#define CG 1024              // col-groups per row (4 cols each)
#define RG 512               // row-groups (8 rows each; last has 6)
#define NWG 2048             // (1024 * 512) / 256
#define XCHUNK 256           // NWG / 8

typedef float f32x4 __attribute__((ext_vector_type(4)));
typedef float f32x2 __attribute__((ext_vector_type(2)));

__global__ __launch_bounds__(256) void conv3x3_r8c4(
    const float* __restrict__ in, const float* __restrict__ wgt,
    const float* __restrict__ bias, float* __restrict__ out) {

    // XCD-aware bijective swizzle (2048 % 8 == 0).
    int b   = blockIdx.x;
    int swz = (b & 7) * XCHUNK + (b >> 3);
    int idx = swz * 256 + (int)threadIdx.x;

    int cg   = idx & (CG - 1);     // 256 consecutive cg per block
    int rg   = idx >> 10;          // uniform within a block
    int x    = cg << 2;            // output col start (multiple of 4)
    int row0 = rg << 3;            // output row start (even)

    float wv[9];
#pragma unroll
    for (int i = 0; i < 9; ++i) wv[i] = wgt[i];
    float bs = bias[0];

    int nr    = (row0 + 8 <= OH) ? 8 : (OH - row0);  // 8, or 6 at rg==511 (uniform)
    int nload = nr + 2;                              // input rows needed (10 or 8)

    // 10 input row-segments of 6 floats each (float4 + guarded float2).
    float r[10][6];
#pragma unroll
    for (int t = 0; t < 10; ++t) {
        if (t < nload) {
            const float* rp = in + (size_t)(row0 + t) * IW + x;
            float4 a = *reinterpret_cast<const float4*>(rp);   // 16B-aligned
            r[t][0] = a.x; r[t][1] = a.y; r[t][2] = a.z; r[t][3] = a.w;
            if (x + 5 < IW) {                                  // false only at x==4092
                float2 e = *reinterpret_cast<const float2*>(rp + 4);
                r[t][4] = e.x; r[t][5] = e.y;
            } else { r[t][4] = 0.f; r[t][5] = 0.f; }
        } else {
#pragma unroll
            for (int j = 0; j < 6; ++j) r[t][j] = 0.f;
        }
    }

    float acc[8][4];
#pragma unroll
    for (int i = 0; i < 8; ++i)
#pragma unroll
        for (int c = 0; c < 4; ++c) acc[i][c] = bs;

    // 288 FMAs: output row orow uses input rows orow..orow+2.
#pragma unroll
    for (int orow = 0; orow < 8; ++orow) {
#pragma unroll
        for (int kh = 0; kh < 3; ++kh) {
            int t = orow + kh;
            float w0 = wv[kh * 3 + 0], w1 = wv[kh * 3 + 1], w2 = wv[kh * 3 + 2];
#pragma unroll
            for (int c = 0; c < 4; ++c)
                acc[orow][c] += w0 * r[t][c] + w1 * r[t][c + 1] + w2 * r[t][c + 2];
        }
    }

    // Stores, identical per-row pattern to the proven R9 kernel:
    // even rows: one f32x4 (16B-aligned; lane stride 16B -> wave-contiguous 1KB).
    // odd rows:  two address-adjacent f32x2 (8B-aligned) that merge in the
    //            write combiner. Nontemporal: output is never re-read.
    int nc = (x + 4 <= OW) ? 4 : (OW - x);           // 4, or 2 at x==4092
#pragma unroll
    for (int orow = 0; orow < 8; ++orow) {
        if (orow < nr) {
            float* op = out + (size_t)(row0 + orow) * OW + x;
            if (nc == 4) {
                if ((orow & 1) == 0) {
                    f32x4 v = { acc[orow][0], acc[orow][1],
                                acc[orow][2], acc[orow][3] };
                    __builtin_nontemporal_store(v, reinterpret_cast<f32x4*>(op));
                } else {
                    f32x2 v0 = { acc[orow][0], acc[orow][1] };
                    f32x2 v1 = { acc[orow][2], acc[orow][3] };
                    __builtin_nontemporal_store(v0, reinterpret_cast<f32x2*>(op));
                    __builtin_nontemporal_store(v1, reinterpret_cast<f32x2*>(op + 2));
                }
            } else {
                f32x2 v0 = { acc[orow][0], acc[orow][1] };
                __builtin_nontemporal_store(v0, reinterpret_cast<f32x2*>(op));
            }
        }
    }
}

extern "C" void kernel_launch(void* const* d_in, const int* in_sizes, int n_in,
                              void* d_out, int out_size, void* d_ws, size_t ws_size,
                              hipStream_t stream) {
    const float* in   = (const float*)d_in[0];
    const float* wgt  = (const float*)d_in[1];
    const float* bias = (const float*)d_in[2];
    float* out        = (float*)d_out;

    conv3x3_r8c4<<<NWG, 256, 0, stream>>>(in, wgt, bias, out);
}